// Round 14
// baseline (121.285 us; speedup 1.0000x reference)
//
#include <hip/hip_runtime.h>

#define SB 8
#define SS 2048
#define SD 1024
#define SH 64

typedef float f32x4 __attribute__((ext_vector_type(4)));
typedef __bf16 bf16x8 __attribute__((ext_vector_type(8)));

__device__ __forceinline__ unsigned short f2bf(float f) {
  union { float f; unsigned int u; } v; v.f = f;
  unsigned int u = v.u;
  unsigned int r = u + 0x7FFFu + ((u >> 16) & 1u);
  return (unsigned short)(r >> 16);
}

__device__ __forceinline__ bf16x8 asbf(f32x4 x) {
  union { f32x4 f; bf16x8 b; } u; u.f = x; return u.b;
}

// Wt[hc][d] = W_{hc/64}[d][hc&63] as bf16, hc in [0,192), d in [0,1024)
__global__ void prep_wt(const float* __restrict__ Wq, const float* __restrict__ Wk,
                        const float* __restrict__ Wv, unsigned short* __restrict__ Wt) {
  int idx = blockIdx.x * 256 + threadIdx.x;
  int hc = idx >> 10, d = idx & 1023;
  const float* W = (hc < 64) ? Wq : (hc < 128) ? Wk : Wv;
  int h = hc & 63;
  Wt[idx] = f2bf(W[d * SH + h]);
}

// QKV projection v4 (r12 form, NT reverted): 512 blocks x 512 thr, 2 blocks/CU.
__global__ void __launch_bounds__(512, 2) proj(
    const float* __restrict__ x, const unsigned short* __restrict__ Wt,
    unsigned short* __restrict__ Q, unsigned short* __restrict__ K,
    unsigned short* __restrict__ Vt) {
  __shared__ unsigned short xs[2][32 * 64];     // 2 x 4 KB A tiles
  __shared__ unsigned short Bl[2][192 * 64];    // 2 x 24 KB B tiles

  int tid = threadIdx.x;
  int w = tid >> 6, lane = tid & 63;
  int l15 = lane & 15, kg = lane >> 4;
  int wr = w >> 2, wc = w & 3;
  int m0 = blockIdx.x * 32;

  int srow = tid >> 4, sseg = tid & 15;
  const float* xp = x + (size_t)(m0 + srow) * SD + sseg * 4;
  int swoff = srow * 64 + (((sseg >> 1) ^ (srow & 7)) << 3) + ((sseg & 1) << 2);

#define STAGEB(tt, buf)                                                          \
  {                                                                              \
    _Pragma("unroll") for (int j = 0; j < 3; ++j) {                              \
      int Lb = w * 1024 + j * 8192 + lane * 16;                                  \
      int c = Lb >> 7, cb = Lb & 127;                                            \
      const char* srcp = (const char*)Wt + (size_t)c * 2048 + (tt) * 128 +       \
                         (cb ^ ((c & 7) << 4));                                  \
      __builtin_amdgcn_global_load_lds(                                          \
          (const __attribute__((address_space(1))) unsigned int*)(const void*)srcp, \
          (__attribute__((address_space(3))) unsigned int*)(void*)                \
              ((char*)&Bl[(buf)][0] + w * 1024 + j * 8192),                      \
          16, 0, 0);                                                             \
    }                                                                            \
  }

#define CVTW(RA, buf)                                                           \
  {                                                                             \
    ushort4 cv;                                                                 \
    cv.x = f2bf((RA).x); cv.y = f2bf((RA).y);                                   \
    cv.z = f2bf((RA).z); cv.w = f2bf((RA).w);                                   \
    *(ushort4*)(&xs[(buf)][0] + swoff) = cv;                                    \
  }

  f32x4 acc[3];
#pragma unroll
  for (int nt = 0; nt < 3; ++nt) acc[nt] = f32x4{0.f, 0.f, 0.f, 0.f};

  float4 ra = *(const float4*)xp;            // x(0)
  STAGEB(0, 0);
  CVTW(ra, 0);
  ra = *(const float4*)(xp + 64);            // x(1)
  __syncthreads();

  for (int t = 0; t < 16; ++t) {
    int cur = t & 1, nxt = (t + 1) & 1;
    if (t < 15) CVTW(ra, nxt);
    if (t < 14) ra = *(const float4*)(xp + (t + 2) * 64);
    if (t < 15) STAGEB(t + 1, nxt);

    const char* Bb = (const char*)&Bl[cur][0];
#pragma unroll
    for (int ks = 0; ks < 2; ++ks) {
      int row = wr * 16 + l15;
      int cg = ks * 4 + kg;
      bf16x8 af = *(const bf16x8*)(&xs[cur][0] + row * 64 + ((cg ^ (row & 7)) << 3));
#pragma unroll
      for (int nt = 0; nt < 3; ++nt) {
        int c = wc * 48 + nt * 16 + l15;
        int kb = (ks * 32 + kg * 8) * 2;
        bf16x8 bfr = *(const bf16x8*)(Bb + c * 128 + (kb ^ ((c & 7) << 4)));
        acc[nt] = __builtin_amdgcn_mfma_f32_16x16x32_bf16(af, bfr, acc[nt], 0, 0, 0);
      }
    }
    __syncthreads();
  }

#pragma unroll
  for (int nt = 0; nt < 3; ++nt) {
    int c = wc * 48 + nt * 16 + l15;
    int mat = c >> 6, h = c & 63;
#pragma unroll
    for (int r = 0; r < 4; ++r) {
      int row = m0 + wr * 16 + kg * 4 + r;
      unsigned short bv = f2bf(acc[nt][r]);
      if (mat == 0) {
        Q[(size_t)row * SH + h] = bv;
      } else if (mat == 1) {
        K[(size_t)row * SH + h] = bv;
      } else {
        int bb = row >> 11, key = row & 2047;
        Vt[((size_t)bb * SH + h) * SS + key] = bv;
      }
    }
  }
}

// Pass A: QK^T + softmax + weight stores ONLY (r12 attn minus PV/combine).
// After softmax, waves purely stream stores -- nothing ever waits on them.
// 1024 blocks x 512 thr, 4 blocks/CU.
__global__ void __launch_bounds__(512, 4) qk_sm(
    const unsigned short* __restrict__ Q, const unsigned short* __restrict__ Kb,
    float* __restrict__ wts) {
  __shared__ float pf[8][16][68];
  __shared__ float mS[8][16], sgS[8][16];

  int b = blockIdx.x & 7, rg = blockIdx.x >> 3;
  int w = threadIdx.x >> 6, lane = threadIdx.x & 63;
  int l15 = lane & 15, kg = lane >> 4;
  int q0 = rg * 16;
  int kv0 = w * 256;

  const unsigned short* Qb  = Q  + (size_t)b * SS * SH;
  const unsigned short* Kbb = Kb + (size_t)b * SS * SH;

  bf16x8 qf[2];
#pragma unroll
  for (int ks = 0; ks < 2; ++ks)
    qf[ks] = *(const bf16x8*)(Qb + (size_t)(q0 + l15) * SH + ks * 32 + kg * 8);

  f32x4 s[4][4];
#pragma unroll
  for (int kt = 0; kt < 4; ++kt)
#pragma unroll
    for (int n = 0; n < 4; ++n) s[kt][n] = f32x4{0.f, 0.f, 0.f, 0.f};

  for (int kt = 0; kt < 4; ++kt) {
#pragma unroll
    for (int ks = 0; ks < 2; ++ks)
#pragma unroll
      for (int n = 0; n < 4; ++n) {
        bf16x8 kf = *(const bf16x8*)(Kbb + (size_t)(kv0 + kt * 64 + n * 16 + l15) * SH + ks * 32 + kg * 8);
        s[kt][n] = __builtin_amdgcn_mfma_f32_16x16x32_bf16(qf[ks], kf, s[kt][n], 0, 0, 0);
      }
  }

  float m[4], sg[4];
#pragma unroll
  for (int r = 0; r < 4; ++r) {
    float mloc = -1e30f;
#pragma unroll
    for (int kt = 0; kt < 4; ++kt)
#pragma unroll
      for (int n = 0; n < 4; ++n) mloc = fmaxf(mloc, s[kt][n][r]);
    mloc *= 0.125f;
#pragma unroll
    for (int off = 1; off < 16; off <<= 1) mloc = fmaxf(mloc, __shfl_xor(mloc, off));
    float ssum = 0.f;
#pragma unroll
    for (int kt = 0; kt < 4; ++kt)
#pragma unroll
      for (int n = 0; n < 4; ++n) {
        float e = __expf(s[kt][n][r] * 0.125f - mloc);
        s[kt][n][r] = e;
        ssum += e;
      }
#pragma unroll
    for (int off = 1; off < 16; off <<= 1) ssum += __shfl_xor(ssum, off);
    m[r] = mloc; sg[r] = ssum;
  }

  if (l15 == 0) {
#pragma unroll
    for (int r = 0; r < 4; ++r) {
      mS[w][kg * 4 + r] = m[r];
      sgS[w][kg * 4 + r] = sg[r];
    }
  }
  __syncthreads();

  float scal[4];
#pragma unroll
  for (int r = 0; r < 4; ++r) {
    int row = kg * 4 + r;
    float M = -1e30f;
#pragma unroll
    for (int ww = 0; ww < 8; ++ww) M = fmaxf(M, mS[ww][row]);
    float Sg = 0.f;
#pragma unroll
    for (int ww = 0; ww < 8; ++ww) Sg += sgS[ww][row] * __expf(mS[ww][row] - M);
    scal[r] = __expf(m[r] - M) / Sg;
  }

  float* wb = wts + (size_t)b * SS * SS;
  for (int kt = 0; kt < 4; ++kt) {
#pragma unroll
    for (int n = 0; n < 4; ++n)
#pragma unroll
      for (int r = 0; r < 4; ++r)
        pf[w][kg * 4 + r][n * 16 + l15] = s[kt][n][r] * scal[r];
    asm volatile("s_waitcnt lgkmcnt(0)" ::: "memory");

#pragma unroll
    for (int i = 0; i < 4; ++i) {
      int row = i * 4 + kg;
      f32x4 pv4 = *(const f32x4*)&pf[w][row][l15 * 4];
      *(f32x4*)(wb + (size_t)(q0 + row) * SS + kv0 + kt * 64 + l15 * 4) = pv4;
    }
  }
}

// Pass B: out = weights x V. Streaming GEMM M=16384, N=64, K=2048.
// A = fp32 weights (134 MB, L3-resident: just written), B = Vt (L2-resident).
// All loads via asm ring: 3 groups x 6 loads in flight, counted vmcnt(12) +
// sched_barrier(0) (rule-18) -- depth plain C++ provably doesn't give (r9).
// 1024 blocks x 512 thr; wave = 16 q-rows x 256-key slice; cf combine.
__global__ void __launch_bounds__(512, 2) wv(
    const float* __restrict__ wts, const unsigned short* __restrict__ Vt,
    float* __restrict__ out) {
  __shared__ float cf[8][16][68];

  int b = blockIdx.x & 7, rg = blockIdx.x >> 3;
  int w = threadIdx.x >> 6, lane = threadIdx.x & 63;
  int l15 = lane & 15, kg = lane >> 4;
  int q0 = rg * 16;
  int kv0 = w * 256;

  const float* ap = wts + (size_t)b * SS * SS + (size_t)(q0 + l15) * SS + kv0 + kg * 8;
  const unsigned short* Vtb = Vt + (size_t)b * SH * SS;

  f32x4 rA0_0, rA0_1, rV0_0, rV0_1, rV0_2, rV0_3;
  f32x4 rA1_0, rA1_1, rV1_0, rV1_1, rV1_2, rV1_3;
  f32x4 rA2_0, rA2_1, rV2_0, rV2_1, rV2_2, rV2_3;

#define VADDR(KT, NH) (Vtb + (size_t)((NH) * 16 + l15) * SS + kv0 + (KT) * 32 + kg * 8)
#define GISSUE(S, KT)                                                                     \
  asm volatile("global_load_dwordx4 %0, %1, off" : "=v"(rA##S##_0) : "v"(ap + (KT) * 32));     \
  asm volatile("global_load_dwordx4 %0, %1, off" : "=v"(rA##S##_1) : "v"(ap + (KT) * 32 + 4)); \
  asm volatile("global_load_dwordx4 %0, %1, off" : "=v"(rV##S##_0) : "v"(VADDR(KT, 0)));       \
  asm volatile("global_load_dwordx4 %0, %1, off" : "=v"(rV##S##_1) : "v"(VADDR(KT, 1)));       \
  asm volatile("global_load_dwordx4 %0, %1, off" : "=v"(rV##S##_2) : "v"(VADDR(KT, 2)));       \
  asm volatile("global_load_dwordx4 %0, %1, off" : "=v"(rV##S##_3) : "v"(VADDR(KT, 3)));
#define GWAIT(N)                            \
  asm volatile("s_waitcnt vmcnt(" #N ")");  \
  __builtin_amdgcn_sched_barrier(0);
#define GCONSUME(S, N)                                                                  \
  GWAIT(N);                                                                             \
  {                                                                                     \
    union { unsigned short us[8]; bf16x8 v; } pu;                                       \
    _Pragma("unroll") for (int i = 0; i < 4; ++i) {                                     \
      pu.us[i] = f2bf(rA##S##_0[i]);                                                    \
      pu.us[4 + i] = f2bf(rA##S##_1[i]);                                                \
    }                                                                                   \
    oacc[0] = __builtin_amdgcn_mfma_f32_16x16x32_bf16(pu.v, asbf(rV##S##_0), oacc[0], 0, 0, 0); \
    oacc[1] = __builtin_amdgcn_mfma_f32_16x16x32_bf16(pu.v, asbf(rV##S##_1), oacc[1], 0, 0, 0); \
    oacc[2] = __builtin_amdgcn_mfma_f32_16x16x32_bf16(pu.v, asbf(rV##S##_2), oacc[2], 0, 0, 0); \
    oacc[3] = __builtin_amdgcn_mfma_f32_16x16x32_bf16(pu.v, asbf(rV##S##_3), oacc[3], 0, 0, 0); \
  }

  f32x4 oacc[4];
#pragma unroll
  for (int nh = 0; nh < 4; ++nh) oacc[nh] = f32x4{0.f, 0.f, 0.f, 0.f};

  // 8 k-groups of 32 keys; 3 groups (18 loads) in flight.
  GISSUE(0, 0); GISSUE(1, 1); GISSUE(2, 2);
  GCONSUME(0, 12); GISSUE(0, 3);
  GCONSUME(1, 12); GISSUE(1, 4);
  GCONSUME(2, 12); GISSUE(2, 5);
  GCONSUME(0, 12); GISSUE(0, 6);
  GCONSUME(1, 12); GISSUE(1, 7);
  GCONSUME(2, 12);
  GCONSUME(0, 6);
  GCONSUME(1, 0);

  // combine partial PV across the 8 waves
#pragma unroll
  for (int nh = 0; nh < 4; ++nh)
#pragma unroll
    for (int r = 0; r < 4; ++r)
      cf[w][kg * 4 + r][nh * 16 + l15] = oacc[nh][r];
  __syncthreads();

  int tid = threadIdx.x;
#pragma unroll
  for (int half = 0; half < 2; ++half) {
    int e = tid + half * 512;
    int row = e >> 6, col = e & 63;
    float ssum = 0.f;
#pragma unroll
    for (int ww = 0; ww < 8; ++ww) ssum += cf[ww][row][col];
    out[((size_t)b * SS + q0 + row) * SH + col] = ssum;
  }
}

extern "C" void kernel_launch(void* const* d_in, const int* in_sizes, int n_in,
                              void* d_out, int out_size, void* d_ws, size_t ws_size,
                              hipStream_t stream) {
  const float* x  = (const float*)d_in[0];
  const float* Wq = (const float*)d_in[1];
  const float* Wk = (const float*)d_in[2];
  const float* Wv = (const float*)d_in[3];

  unsigned short* Wt = (unsigned short*)d_ws;                 // 192*1024
  unsigned short* Q  = Wt + 192 * 1024;                       // 16384*64
  unsigned short* K  = Q + 16384 * 64;                        // 16384*64
  unsigned short* Vt = K + 16384 * 64;                        // 8*64*2048

  float* out = (float*)d_out;
  float* wts = out + (size_t)SB * SS * SH;

  prep_wt<<<768, 256, 0, stream>>>(Wq, Wk, Wv, Wt);
  proj<<<512, 512, 0, stream>>>(x, Wt, Q, K, Vt);
  qk_sm<<<1024, 512, 0, stream>>>(Q, K, wts);
  wv<<<1024, 512, 0, stream>>>(wts, Vt, out);
}

// Round 15
// 96.064 us; speedup vs baseline: 1.2625x; 1.2625x over previous
//
#include <hip/hip_runtime.h>

#define SB 8
#define SS 2048
#define SD 1024
#define SH 64

typedef float f32x4 __attribute__((ext_vector_type(4)));
typedef __bf16 bf16x8 __attribute__((ext_vector_type(8)));

__device__ __forceinline__ unsigned short f2bf(float f) {
  union { float f; unsigned int u; } v; v.f = f;
  unsigned int u = v.u;
  unsigned int r = u + 0x7FFFu + ((u >> 16) & 1u);
  return (unsigned short)(r >> 16);
}

// Wt[hc][d] = W_{hc/64}[d][hc&63] as bf16, hc in [0,192), d in [0,1024)
__global__ void prep_wt(const float* __restrict__ Wq, const float* __restrict__ Wk,
                        const float* __restrict__ Wv, unsigned short* __restrict__ Wt) {
  int idx = blockIdx.x * 256 + threadIdx.x;
  int hc = idx >> 10, d = idx & 1023;
  const float* W = (hc < 64) ? Wq : (hc < 128) ? Wk : Wv;
  int h = hc & 63;
  Wt[idx] = f2bf(W[d * SH + h]);
}

// QKV projection v4 (r12, best measured ~29us): 512 blocks x 512 thr, 2 blocks/CU.
__global__ void __launch_bounds__(512, 2) proj(
    const float* __restrict__ x, const unsigned short* __restrict__ Wt,
    unsigned short* __restrict__ Q, unsigned short* __restrict__ K,
    unsigned short* __restrict__ Vt) {
  __shared__ unsigned short xs[2][32 * 64];     // 2 x 4 KB A tiles
  __shared__ unsigned short Bl[2][192 * 64];    // 2 x 24 KB B tiles

  int tid = threadIdx.x;
  int w = tid >> 6, lane = tid & 63;
  int l15 = lane & 15, kg = lane >> 4;
  int wr = w >> 2, wc = w & 3;
  int m0 = blockIdx.x * 32;

  int srow = tid >> 4, sseg = tid & 15;
  const float* xp = x + (size_t)(m0 + srow) * SD + sseg * 4;
  int swoff = srow * 64 + (((sseg >> 1) ^ (srow & 7)) << 3) + ((sseg & 1) << 2);

#define STAGEB(tt, buf)                                                          \
  {                                                                              \
    _Pragma("unroll") for (int j = 0; j < 3; ++j) {                              \
      int Lb = w * 1024 + j * 8192 + lane * 16;                                  \
      int c = Lb >> 7, cb = Lb & 127;                                            \
      const char* srcp = (const char*)Wt + (size_t)c * 2048 + (tt) * 128 +       \
                         (cb ^ ((c & 7) << 4));                                  \
      __builtin_amdgcn_global_load_lds(                                          \
          (const __attribute__((address_space(1))) unsigned int*)(const void*)srcp, \
          (__attribute__((address_space(3))) unsigned int*)(void*)                \
              ((char*)&Bl[(buf)][0] + w * 1024 + j * 8192),                      \
          16, 0, 0);                                                             \
    }                                                                            \
  }

#define CVTW(RA, buf)                                                           \
  {                                                                             \
    ushort4 cv;                                                                 \
    cv.x = f2bf((RA).x); cv.y = f2bf((RA).y);                                   \
    cv.z = f2bf((RA).z); cv.w = f2bf((RA).w);                                   \
    *(ushort4*)(&xs[(buf)][0] + swoff) = cv;                                    \
  }

  f32x4 acc[3];
#pragma unroll
  for (int nt = 0; nt < 3; ++nt) acc[nt] = f32x4{0.f, 0.f, 0.f, 0.f};

  float4 ra = *(const float4*)xp;            // x(0)
  STAGEB(0, 0);
  CVTW(ra, 0);
  ra = *(const float4*)(xp + 64);            // x(1)
  __syncthreads();

  for (int t = 0; t < 16; ++t) {
    int cur = t & 1, nxt = (t + 1) & 1;
    if (t < 15) CVTW(ra, nxt);
    if (t < 14) ra = *(const float4*)(xp + (t + 2) * 64);
    if (t < 15) STAGEB(t + 1, nxt);

    const char* Bb = (const char*)&Bl[cur][0];
#pragma unroll
    for (int ks = 0; ks < 2; ++ks) {
      int row = wr * 16 + l15;
      int cg = ks * 4 + kg;
      bf16x8 af = *(const bf16x8*)(&xs[cur][0] + row * 64 + ((cg ^ (row & 7)) << 3));
#pragma unroll
      for (int nt = 0; nt < 3; ++nt) {
        int c = wc * 48 + nt * 16 + l15;
        int kb = (ks * 32 + kg * 8) * 2;
        bf16x8 bfr = *(const bf16x8*)(Bb + c * 128 + (kb ^ ((c & 7) << 4)));
        acc[nt] = __builtin_amdgcn_mfma_f32_16x16x32_bf16(af, bfr, acc[nt], 0, 0, 0);
      }
    }
    __syncthreads();
  }

#pragma unroll
  for (int nt = 0; nt < 3; ++nt) {
    int c = wc * 48 + nt * 16 + l15;
    int mat = c >> 6, h = c & 63;
#pragma unroll
    for (int r = 0; r < 4; ++r) {
      int row = m0 + wr * 16 + kg * 4 + r;
      unsigned short bv = f2bf(acc[nt][r]);
      if (mat == 0) {
        Q[(size_t)row * SH + h] = bv;
      } else if (mat == 1) {
        K[(size_t)row * SH + h] = bv;
      } else {
        int bb = row >> 11, key = row & 2047;
        Vt[((size_t)bb * SH + h) * SS + key] = bv;
      }
    }
  }
}

// Attention, single pass, KV-split x8 (r2 structure). Phase-C change vs r12:
// weight stores go DIRECTLY from registers (coalesced dword stores, 4x64B full
// lines per instr) with no LDS dependency; a slim bf16 psh tile exists only
// for the PV A-frag transpose. psh aliases the f32 combine arena (disjoint
// lifetimes). 1024 blocks x 512 thr, ~35 KB LDS -> 4 blocks/CU.
__global__ void __launch_bounds__(512, 4) attn(
    const unsigned short* __restrict__ Q, const unsigned short* __restrict__ Kb,
    const unsigned short* __restrict__ Vt, float* __restrict__ out,
    float* __restrict__ wts) {
  __shared__ __align__(16) float shbuf[8 * 16 * 68];  // 34.8 KB arena
  __shared__ float mS[8][16], sgS[8][16];
  unsigned short (*psh)[16][72] = (unsigned short (*)[16][72])shbuf;  // 18.4 KB
  float (*cf)[16][68] = (float (*)[16][68])shbuf;

  int b = blockIdx.x & 7, rg = blockIdx.x >> 3;
  int w = threadIdx.x >> 6, lane = threadIdx.x & 63;
  int l15 = lane & 15, kg = lane >> 4;
  int q0 = rg * 16;
  int kv0 = w * 256;

  const unsigned short* Qb  = Q  + (size_t)b * SS * SH;
  const unsigned short* Kbb = Kb + (size_t)b * SS * SH;
  const unsigned short* Vtb = Vt + (size_t)b * SH * SS;

  bf16x8 qf[2];
#pragma unroll
  for (int ks = 0; ks < 2; ++ks)
    qf[ks] = *(const bf16x8*)(Qb + (size_t)(q0 + l15) * SH + ks * 32 + kg * 8);

  // ---- QK^T: s[kt][n] row = q (kg*4+r), col = k (n*16+l15)
  f32x4 s[4][4];
#pragma unroll
  for (int kt = 0; kt < 4; ++kt)
#pragma unroll
    for (int n = 0; n < 4; ++n) s[kt][n] = f32x4{0.f, 0.f, 0.f, 0.f};

  for (int kt = 0; kt < 4; ++kt) {
#pragma unroll
    for (int ks = 0; ks < 2; ++ks)
#pragma unroll
      for (int n = 0; n < 4; ++n) {
        bf16x8 kf = *(const bf16x8*)(Kbb + (size_t)(kv0 + kt * 64 + n * 16 + l15) * SH + ks * 32 + kg * 8);
        s[kt][n] = __builtin_amdgcn_mfma_f32_16x16x32_bf16(qf[ks], kf, s[kt][n], 0, 0, 0);
      }
  }

  // ---- softmax stats (16-lane-parallel reduce per row)
  float m[4], sg[4];
#pragma unroll
  for (int r = 0; r < 4; ++r) {
    float mloc = -1e30f;
#pragma unroll
    for (int kt = 0; kt < 4; ++kt)
#pragma unroll
      for (int n = 0; n < 4; ++n) mloc = fmaxf(mloc, s[kt][n][r]);
    mloc *= 0.125f;
#pragma unroll
    for (int off = 1; off < 16; off <<= 1) mloc = fmaxf(mloc, __shfl_xor(mloc, off));
    float ssum = 0.f;
#pragma unroll
    for (int kt = 0; kt < 4; ++kt)
#pragma unroll
      for (int n = 0; n < 4; ++n) {
        float e = __expf(s[kt][n][r] * 0.125f - mloc);
        s[kt][n][r] = e;
        ssum += e;
      }
#pragma unroll
    for (int off = 1; off < 16; off <<= 1) ssum += __shfl_xor(ssum, off);
    m[r] = mloc; sg[r] = ssum;
  }

  if (l15 == 0) {
#pragma unroll
    for (int r = 0; r < 4; ++r) {
      mS[w][kg * 4 + r] = m[r];
      sgS[w][kg * 4 + r] = sg[r];
    }
  }
  __syncthreads();

  float scal[4];
#pragma unroll
  for (int r = 0; r < 4; ++r) {
    int row = kg * 4 + r;
    float M = -1e30f;
#pragma unroll
    for (int ww = 0; ww < 8; ++ww) M = fmaxf(M, mS[ww][row]);
    float Sg = 0.f;
#pragma unroll
    for (int ww = 0; ww < 8; ++ww) Sg += sgS[ww][row] * __expf(mS[ww][row] - M);
    scal[r] = __expf(m[r] - M) / Sg;
  }

  float* wb = wts + (size_t)b * SS * SS;
  f32x4 oacc[4];
#pragma unroll
  for (int nh = 0; nh < 4; ++nh) oacc[nh] = f32x4{0.f, 0.f, 0.f, 0.f};

  // ---- phase C: per 64-key tile
  // stores straight from regs (no LDS dep); psh bf16 only feeds the PV A-frag.
  for (int kt = 0; kt < 4; ++kt) {
#pragma unroll
    for (int n = 0; n < 4; ++n)
#pragma unroll
      for (int r = 0; r < 4; ++r) {
        float p = s[kt][n][r] * scal[r];
        wb[(size_t)(q0 + kg * 4 + r) * SS + kv0 + kt * 64 + n * 16 + l15] = p;
        psh[w][kg * 4 + r][n * 16 + l15] = f2bf(p);
      }

#pragma unroll
    for (int ks = 0; ks < 2; ++ks) {
      bf16x8 pu = *(const bf16x8*)&psh[w][l15][ks * 32 + kg * 8];
#pragma unroll
      for (int nh = 0; nh < 4; ++nh) {
        bf16x8 vf = *(const bf16x8*)(Vtb + (size_t)(nh * 16 + l15) * SS + kv0 + kt * 64 + ks * 32 + kg * 8);
        oacc[nh] = __builtin_amdgcn_mfma_f32_16x16x32_bf16(pu, vf, oacc[nh], 0, 0, 0);
      }
    }
  }

  // ---- psh lifetime ends; alias arena as cf for the partial-PV combine
  __syncthreads();
#pragma unroll
  for (int nh = 0; nh < 4; ++nh)
#pragma unroll
    for (int r = 0; r < 4; ++r)
      cf[w][kg * 4 + r][nh * 16 + l15] = oacc[nh][r];
  __syncthreads();

  int tid = threadIdx.x;
#pragma unroll
  for (int half = 0; half < 2; ++half) {
    int e = tid + half * 512;
    int row = e >> 6, col = e & 63;
    float ssum = 0.f;
#pragma unroll
    for (int ww = 0; ww < 8; ++ww) ssum += cf[ww][row][col];
    out[((size_t)b * SS + q0 + row) * SH + col] = ssum;
  }
}

extern "C" void kernel_launch(void* const* d_in, const int* in_sizes, int n_in,
                              void* d_out, int out_size, void* d_ws, size_t ws_size,
                              hipStream_t stream) {
  const float* x  = (const float*)d_in[0];
  const float* Wq = (const float*)d_in[1];
  const float* Wk = (const float*)d_in[2];
  const float* Wv = (const float*)d_in[3];

  unsigned short* Wt = (unsigned short*)d_ws;                 // 192*1024
  unsigned short* Q  = Wt + 192 * 1024;                       // 16384*64
  unsigned short* K  = Q + 16384 * 64;                        // 16384*64
  unsigned short* Vt = K + 16384 * 64;                        // 8*64*2048

  float* out = (float*)d_out;
  float* wts = out + (size_t)SB * SS * SH;

  prep_wt<<<768, 256, 0, stream>>>(Wq, Wk, Wv, Wt);
  proj<<<512, 512, 0, stream>>>(x, Wt, Q, K, Vt);
  attn<<<1024, 512, 0, stream>>>(Q, K, Vt, out, wts);
}

// Round 16
// 95.239 us; speedup vs baseline: 1.2735x; 1.0087x over previous
//
#include <hip/hip_runtime.h>

#define SB 8
#define SS 2048
#define SD 1024
#define SH 64

typedef float f32x4 __attribute__((ext_vector_type(4)));
typedef __bf16 bf16x8 __attribute__((ext_vector_type(8)));

__device__ __forceinline__ unsigned short f2bf(float f) {
  union { float f; unsigned int u; } v; v.f = f;
  unsigned int u = v.u;
  unsigned int r = u + 0x7FFFu + ((u >> 16) & 1u);
  return (unsigned short)(r >> 16);
}

// Wt[hc][d] = W_{hc/64}[d][hc&63] as bf16, hc in [0,192), d in [0,1024)
__global__ void prep_wt(const float* __restrict__ Wq, const float* __restrict__ Wk,
                        const float* __restrict__ Wv, unsigned short* __restrict__ Wt) {
  int idx = blockIdx.x * 256 + threadIdx.x;
  int hc = idx >> 10, d = idx & 1023;
  const float* W = (hc < 64) ? Wq : (hc < 128) ? Wk : Wv;
  int h = hc & 63;
  Wt[idx] = f2bf(W[d * SH + h]);
}

// QKV projection v5: ALL staging via global_load_lds + counted vmcnt barriers.
// A (x, f32) in a 4-buffer ring, prefetch depth 2 (covers ~900cy HBM latency);
// B (Wt) 2-buffer, depth 1 (L2-resident). Per step issue order: B(t+1) then
// A(t+2) LAST -> s_waitcnt vmcnt(1) retires oldest-first (m135): {A(t+1),
// B(t+1)} drained, A(t+2) stays in flight ACROSS the raw s_barrier (T4).
// f32->bf16 cvt moved to A-frag read. LDS 4x8K + 2x24K = 80KB -> 2 blocks/CU.
__global__ void __launch_bounds__(512, 2) proj(
    const float* __restrict__ x, const unsigned short* __restrict__ Wt,
    unsigned short* __restrict__ Q, unsigned short* __restrict__ K,
    unsigned short* __restrict__ Vt) {
  __shared__ float xs_f[4][32 * 64];            // 4 x 8 KB A tiles (f32)
  __shared__ unsigned short Bl[2][192 * 64];    // 2 x 24 KB B tiles

  int tid = threadIdx.x;
  int w = tid >> 6, lane = tid & 63;
  int l15 = lane & 15, kg = lane >> 4;
  int wr = w >> 2, wc = w & 3;
  int m0 = blockIdx.x * 32;

  // A DMA source map (pre-swizzled so linear LDS dest ^ read-swizzle match):
  // lane covers f32 idx L=(w*64+lane)*4: row=L>>6, col=L&63.
  int arow = ((w * 64 + lane) >> 4);           // = w*4 + (lane>>4)
  int acol = (lane & 15) * 4;
  int agrp = acol >> 3, awithin = acol & 7;
  const float* asrc = x + (size_t)(m0 + arow) * SD +
                      (((agrp ^ (arow & 7)) << 3) + awithin);

#define STAGEA(tt, buf)                                                          \
  {                                                                              \
    __builtin_amdgcn_global_load_lds(                                            \
        (const __attribute__((address_space(1))) unsigned int*)(const void*)     \
            (asrc + (tt) * 64),                                                  \
        (__attribute__((address_space(3))) unsigned int*)(void*)                 \
            ((char*)&xs_f[(buf)][0] + w * 1024),                                 \
        16, 0, 0);                                                               \
  }

#define STAGEB(tt, buf)                                                          \
  {                                                                              \
    _Pragma("unroll") for (int j = 0; j < 3; ++j) {                              \
      int Lb = w * 1024 + j * 8192 + lane * 16;                                  \
      int c = Lb >> 7, cb = Lb & 127;                                            \
      const char* srcp = (const char*)Wt + (size_t)c * 2048 + (tt) * 128 +       \
                         (cb ^ ((c & 7) << 4));                                  \
      __builtin_amdgcn_global_load_lds(                                          \
          (const __attribute__((address_space(1))) unsigned int*)(const void*)srcp, \
          (__attribute__((address_space(3))) unsigned int*)(void*)                \
              ((char*)&Bl[(buf)][0] + w * 1024 + j * 8192),                      \
          16, 0, 0);                                                             \
    }                                                                            \
  }

  f32x4 acc[3];
#pragma unroll
  for (int nt = 0; nt < 3; ++nt) acc[nt] = f32x4{0.f, 0.f, 0.f, 0.f};

  // Prologue: FIFO = [A0, B0x3, A1] -> vmcnt(1): A0,B0 done, A1 in flight.
  STAGEA(0, 0);
  STAGEB(0, 0);
  STAGEA(1, 1);
  asm volatile("s_waitcnt vmcnt(1) lgkmcnt(0)" ::: "memory");
  __builtin_amdgcn_sched_barrier(0);
  __builtin_amdgcn_s_barrier();
  __builtin_amdgcn_sched_barrier(0);

  for (int t = 0; t < 16; ++t) {
    int abuf = t & 3, bbuf = t & 1;
    // issue next tiles FIRST (overlap with this step's compute)
    if (t < 15) STAGEB(t + 1, (t + 1) & 1);
    if (t < 14) STAGEA(t + 2, (t + 2) & 3);

    const char* Bb = (const char*)&Bl[bbuf][0];
#pragma unroll
    for (int ks = 0; ks < 2; ++ks) {
      int row = wr * 16 + l15;
      int cg = ks * 4 + kg;
      const float* ap = &xs_f[abuf][row * 64 + ((cg ^ (row & 7)) << 3)];
      f32x4 a0 = *(const f32x4*)ap;
      f32x4 a1 = *(const f32x4*)(ap + 4);
      union { unsigned short us[8]; bf16x8 v; } cvu;
#pragma unroll
      for (int i = 0; i < 4; ++i) { cvu.us[i] = f2bf(a0[i]); cvu.us[4 + i] = f2bf(a1[i]); }
#pragma unroll
      for (int nt = 0; nt < 3; ++nt) {
        int c = wc * 48 + nt * 16 + l15;
        int kb = (ks * 32 + kg * 8) * 2;
        bf16x8 bfr = *(const bf16x8*)(Bb + c * 128 + (kb ^ ((c & 7) << 4)));
        acc[nt] = __builtin_amdgcn_mfma_f32_16x16x32_bf16(cvu.v, bfr, acc[nt], 0, 0, 0);
      }
    }

    // Counted drain: keep A(t+2) in flight across the barrier (T4).
    if (t < 14) {
      asm volatile("s_waitcnt vmcnt(1) lgkmcnt(0)" ::: "memory");
    } else {
      asm volatile("s_waitcnt vmcnt(0) lgkmcnt(0)" ::: "memory");
    }
    __builtin_amdgcn_sched_barrier(0);
    __builtin_amdgcn_s_barrier();
    __builtin_amdgcn_sched_barrier(0);
  }

#pragma unroll
  for (int nt = 0; nt < 3; ++nt) {
    int c = wc * 48 + nt * 16 + l15;
    int mat = c >> 6, h = c & 63;
#pragma unroll
    for (int r = 0; r < 4; ++r) {
      int row = m0 + wr * 16 + kg * 4 + r;
      unsigned short bv = f2bf(acc[nt][r]);
      if (mat == 0) {
        Q[(size_t)row * SH + h] = bv;
      } else if (mat == 1) {
        K[(size_t)row * SH + h] = bv;
      } else {
        int bb = row >> 11, key = row & 2047;
        Vt[((size_t)bb * SH + h) * SS + key] = bv;
      }
    }
  }
}

// Attention (r12 exact copy — best measured, 93.0 us total config).
// Single pass, KV-split x8. 1024 blocks x 512 thr, 4 blocks/CU.
__global__ void __launch_bounds__(512, 4) attn(
    const unsigned short* __restrict__ Q, const unsigned short* __restrict__ Kb,
    const unsigned short* __restrict__ Vt, float* __restrict__ out,
    float* __restrict__ wts) {
  __shared__ float pf[8][16][68];
  __shared__ float mS[8][16], sgS[8][16];

  int b = blockIdx.x & 7, rg = blockIdx.x >> 3;
  int w = threadIdx.x >> 6, lane = threadIdx.x & 63;
  int l15 = lane & 15, kg = lane >> 4;
  int q0 = rg * 16;
  int kv0 = w * 256;

  const unsigned short* Qb  = Q  + (size_t)b * SS * SH;
  const unsigned short* Kbb = Kb + (size_t)b * SS * SH;
  const unsigned short* Vtb = Vt + (size_t)b * SH * SS;

  bf16x8 qf[2];
#pragma unroll
  for (int ks = 0; ks < 2; ++ks)
    qf[ks] = *(const bf16x8*)(Qb + (size_t)(q0 + l15) * SH + ks * 32 + kg * 8);

  f32x4 s[4][4];
#pragma unroll
  for (int kt = 0; kt < 4; ++kt)
#pragma unroll
    for (int n = 0; n < 4; ++n) s[kt][n] = f32x4{0.f, 0.f, 0.f, 0.f};

  for (int kt = 0; kt < 4; ++kt) {
#pragma unroll
    for (int ks = 0; ks < 2; ++ks)
#pragma unroll
      for (int n = 0; n < 4; ++n) {
        bf16x8 kf = *(const bf16x8*)(Kbb + (size_t)(kv0 + kt * 64 + n * 16 + l15) * SH + ks * 32 + kg * 8);
        s[kt][n] = __builtin_amdgcn_mfma_f32_16x16x32_bf16(qf[ks], kf, s[kt][n], 0, 0, 0);
      }
  }

  float m[4], sg[4];
#pragma unroll
  for (int r = 0; r < 4; ++r) {
    float mloc = -1e30f;
#pragma unroll
    for (int kt = 0; kt < 4; ++kt)
#pragma unroll
      for (int n = 0; n < 4; ++n) mloc = fmaxf(mloc, s[kt][n][r]);
    mloc *= 0.125f;
#pragma unroll
    for (int off = 1; off < 16; off <<= 1) mloc = fmaxf(mloc, __shfl_xor(mloc, off));
    float ssum = 0.f;
#pragma unroll
    for (int kt = 0; kt < 4; ++kt)
#pragma unroll
      for (int n = 0; n < 4; ++n) {
        float e = __expf(s[kt][n][r] * 0.125f - mloc);
        s[kt][n][r] = e;
        ssum += e;
      }
#pragma unroll
    for (int off = 1; off < 16; off <<= 1) ssum += __shfl_xor(ssum, off);
    m[r] = mloc; sg[r] = ssum;
  }

  if (l15 == 0) {
#pragma unroll
    for (int r = 0; r < 4; ++r) {
      mS[w][kg * 4 + r] = m[r];
      sgS[w][kg * 4 + r] = sg[r];
    }
  }
  __syncthreads();

  float scal[4];
#pragma unroll
  for (int r = 0; r < 4; ++r) {
    int row = kg * 4 + r;
    float M = -1e30f;
#pragma unroll
    for (int ww = 0; ww < 8; ++ww) M = fmaxf(M, mS[ww][row]);
    float Sg = 0.f;
#pragma unroll
    for (int ww = 0; ww < 8; ++ww) Sg += sgS[ww][row] * __expf(mS[ww][row] - M);
    scal[r] = __expf(m[r] - M) / Sg;
  }

  float* wb = wts + (size_t)b * SS * SS;
  f32x4 oacc[4];
#pragma unroll
  for (int nh = 0; nh < 4; ++nh) oacc[nh] = f32x4{0.f, 0.f, 0.f, 0.f};

  for (int kt = 0; kt < 4; ++kt) {
#pragma unroll
    for (int n = 0; n < 4; ++n)
#pragma unroll
      for (int r = 0; r < 4; ++r)
        pf[w][kg * 4 + r][n * 16 + l15] = s[kt][n][r] * scal[r];
    asm volatile("s_waitcnt lgkmcnt(0)" ::: "memory");

#pragma unroll
    for (int i = 0; i < 4; ++i) {
      int row = i * 4 + kg;
      f32x4 pv4 = *(const f32x4*)&pf[w][row][l15 * 4];
      *(f32x4*)(wb + (size_t)(q0 + row) * SS + kv0 + kt * 64 + l15 * 4) = pv4;
    }

#pragma unroll
    for (int ks = 0; ks < 2; ++ks) {
      f32x4 pa = *(const f32x4*)&pf[w][l15][ks * 32 + kg * 8];
      f32x4 pb = *(const f32x4*)&pf[w][l15][ks * 32 + kg * 8 + 4];
      union { unsigned short us[8]; bf16x8 v; } pu;
#pragma unroll
      for (int i = 0; i < 4; ++i) { pu.us[i] = f2bf(pa[i]); pu.us[4 + i] = f2bf(pb[i]); }
#pragma unroll
      for (int nh = 0; nh < 4; ++nh) {
        bf16x8 vf = *(const bf16x8*)(Vtb + (size_t)(nh * 16 + l15) * SS + kv0 + kt * 64 + ks * 32 + kg * 8);
        oacc[nh] = __builtin_amdgcn_mfma_f32_16x16x32_bf16(pu.v, vf, oacc[nh], 0, 0, 0);
      }
    }
  }

#pragma unroll
  for (int nh = 0; nh < 4; ++nh)
#pragma unroll
    for (int r = 0; r < 4; ++r)
      pf[w][kg * 4 + r][nh * 16 + l15] = oacc[nh][r];
  __syncthreads();

  int tid = threadIdx.x;
#pragma unroll
  for (int half = 0; half < 2; ++half) {
    int e = tid + half * 512;
    int row = e >> 6, col = e & 63;
    float ssum = 0.f;
#pragma unroll
    for (int ww = 0; ww < 8; ++ww) ssum += pf[ww][row][col];
    out[((size_t)b * SS + q0 + row) * SH + col] = ssum;
  }
}

extern "C" void kernel_launch(void* const* d_in, const int* in_sizes, int n_in,
                              void* d_out, int out_size, void* d_ws, size_t ws_size,
                              hipStream_t stream) {
  const float* x  = (const float*)d_in[0];
  const float* Wq = (const float*)d_in[1];
  const float* Wk = (const float*)d_in[2];
  const float* Wv = (const float*)d_in[3];

  unsigned short* Wt = (unsigned short*)d_ws;                 // 192*1024
  unsigned short* Q  = Wt + 192 * 1024;                       // 16384*64
  unsigned short* K  = Q + 16384 * 64;                        // 16384*64
  unsigned short* Vt = K + 16384 * 64;                        // 8*64*2048

  float* out = (float*)d_out;
  float* wts = out + (size_t)SB * SS * SH;

  prep_wt<<<768, 256, 0, stream>>>(Wq, Wk, Wv, Wt);
  proj<<<512, 512, 0, stream>>>(x, Wt, Q, K, Vt);
  attn<<<1024, 512, 0, stream>>>(Q, K, Vt, out, wts);
}